// Round 6
// baseline (506.781 us; speedup 1.0000x reference)
//
#include <hip/hip_runtime.h>
#include <math.h>

#define EPSV 1e-5f
#define BINS 16384   // 64KB LDS histogram window
#define SLICES 32    // edge slices per window

typedef _Float16 h16;
typedef _Float16 half8 __attribute__((ext_vector_type(8)));
typedef float f32x4 __attribute__((ext_vector_type(4)));

static __device__ __forceinline__ float h2f(unsigned int u16) {
  unsigned short s = (unsigned short)u16;
  h16 h;
  __builtin_memcpy(&h, &s, 2);
  return (float)h;
}

// ---------------------------------------------------------------- zero (int4)
__global__ __launch_bounds__(256) void k_zero(int4* p, long long n4) {
  long long i = (long long)blockIdx.x * blockDim.x + threadIdx.x;
  long long stride = (long long)gridDim.x * blockDim.x;
  for (; i < n4; i += stride) p[i] = make_int4(0, 0, 0, 0);
}

// ---------------------------------------------------------------- degree: LDS window histogram + coalesced merge
// grid = windows*SLICES; block (w,s): histogram slice s's dsts in window w.
__global__ __launch_bounds__(256) void k_deg2(const int* __restrict__ ei,
                                              int* __restrict__ cnt, int E, int N) {
  __shared__ int hist[BINS];
  int w = blockIdx.x / SLICES, s = blockIdx.x % SLICES;
  int wlo = w * BINS, whi = wlo + BINS;
  long long elo = (long long)s * E / SLICES;
  long long ehi = (long long)(s + 1) * E / SLICES;
  for (int b = threadIdx.x; b < BINS; b += 256) hist[b] = 0;
  __syncthreads();
  for (long long i = elo + threadIdx.x; i < ehi; i += 256) {
    int d = ei[E + i];
    if (d >= wlo && d < whi) atomicAdd(&hist[d - wlo], 1);
  }
  __syncthreads();
  for (int b = threadIdx.x; b < BINS; b += 256) {
    int g = wlo + b;
    if (g < N) atomicAdd(&cnt[g], hist[b]);  // consecutive lanes -> consecutive addrs
  }
}

// ---------------------------------------------------------------- scan step 1: per-1024-chunk sums
__global__ __launch_bounds__(256) void k_bsum(const int* __restrict__ cnt,
                                              int* __restrict__ bsum, int N) {
  int b = blockIdx.x, t = threadIdx.x;
  int base = b << 10;
  int v = 0;
#pragma unroll
  for (int i = 0; i < 4; ++i) {
    int idx = base + t + i * 256;
    if (idx < N) v += cnt[idx];
  }
  __shared__ int s[256];
  s[t] = v;
  __syncthreads();
  for (int off = 128; off > 0; off >>= 1) {
    if (t < off) s[t] += s[t + off];
    __syncthreads();
  }
  if (t == 0) bsum[b] = s[0];
}

// ---------------------------------------------------------------- scan step 2: exclusive scan of chunk sums (1 block)
__global__ __launch_bounds__(256) void k_bscan(int* __restrict__ bsum, int nb,
                                               int* __restrict__ offs_last, int E) {
  int t = threadIdx.x;
  int per = (nb + 255) / 256;
  int lo = t * per, hi = min(lo + per, nb);
  int tot = 0;
  for (int i = lo; i < hi; ++i) tot += bsum[i];
  __shared__ int s[256];
  s[t] = tot;
  __syncthreads();
  for (int off = 1; off < 256; off <<= 1) {
    int u = (t >= off) ? s[t - off] : 0;
    __syncthreads();
    s[t] += u;
    __syncthreads();
  }
  int run = s[t] - tot;
  for (int i = lo; i < hi; ++i) {
    int v = bsum[i];
    bsum[i] = run;
    run += v;
  }
  if (t == 0) *offs_last = E;  // offs[N] = E
}

// ---------------------------------------------------------------- scan step 3: per-chunk exclusive scan + base; offs, cursor, dinv
__global__ __launch_bounds__(256) void k_scan3(const int* __restrict__ cnt,
                                               const int* __restrict__ bsum,
                                               int* __restrict__ offs,
                                               int* __restrict__ cursor,
                                               float* __restrict__ dinv, int N) {
  int b = blockIdx.x, t = threadIdx.x;
  int base = (b << 10) + t * 4;
  int c[4];
  int tot = 0;
#pragma unroll
  for (int i = 0; i < 4; ++i) {
    int idx = base + i;
    c[i] = (idx < N) ? cnt[idx] : 0;
    tot += c[i];
  }
  __shared__ int s[256];
  s[t] = tot;
  __syncthreads();
  for (int off = 1; off < 256; off <<= 1) {
    int u = (t >= off) ? s[t - off] : 0;
    __syncthreads();
    s[t] += u;
    __syncthreads();
  }
  int run = s[t] - tot + bsum[b];
#pragma unroll
  for (int i = 0; i < 4; ++i) {
    int idx = base + i;
    if (idx < N) {
      offs[idx] = run;
      cursor[idx] = run;
      dinv[idx] = rsqrtf((float)c[i] + 1.f);
      run += c[i];
    }
  }
}

// ---------------------------------------------------------------- CSR scatter: LDS hist + bulk reserve + LDS cursor alloc
// No random global atomics: per-bin chunk reservation is coalesced.
__global__ __launch_bounds__(256) void k_scat2(const int* __restrict__ ei,
                                               int* __restrict__ cursor,
                                               int* __restrict__ csr, int E, int N) {
  __shared__ int hist[BINS];
  int w = blockIdx.x / SLICES, s = blockIdx.x % SLICES;
  int wlo = w * BINS, whi = wlo + BINS;
  long long elo = (long long)s * E / SLICES;
  long long ehi = (long long)(s + 1) * E / SLICES;
  for (int b = threadIdx.x; b < BINS; b += 256) hist[b] = 0;
  __syncthreads();
  for (long long i = elo + threadIdx.x; i < ehi; i += 256) {
    int d = ei[E + i];
    if (d >= wlo && d < whi) atomicAdd(&hist[d - wlo], 1);
  }
  __syncthreads();
  for (int b = threadIdx.x; b < BINS; b += 256) {
    int g = wlo + b;
    int h = hist[b];
    int base = 0;
    if (g < N) base = atomicAdd(&cursor[g], h);  // coalesced reserve (returns old)
    hist[b] = base;                              // LDS bin cursor = reserved base
  }
  __syncthreads();
  for (long long i = elo + threadIdx.x; i < ehi; i += 256) {
    int d = ei[E + i];                           // L2-hot (read in pass 1)
    if (d >= wlo && d < whi) {
      int pos = atomicAdd(&hist[d - wlo], 1);    // ds_add_rtn
      csr[pos] = ei[i];                          // window-dense write
    }
  }
}

// ---------------------------------------------------------------- GEMM1 (MFMA): h[N,64](f16) = x[N,128](f32) @ W[128,64](f32)
// A: row=lane&15, k=(lane>>4)*8+j ; B: col=lane&15, same k ;
// D: col=lane&15, row=(lane>>4)*4+reg   [m89/m91-verified layouts]
__global__ __launch_bounds__(256, 1) void k_gemm1(const float* __restrict__ x,
                                                  const float* __restrict__ W,
                                                  h16* __restrict__ h, int N) {
  int lane = threadIdx.x & 63;
  int wave = threadIdx.x >> 6;
  int q = lane >> 4, r16 = lane & 15;
  half8 bf[4][4];  // [n_tile][k_step], W is L2-resident
#pragma unroll
  for (int t = 0; t < 4; ++t)
#pragma unroll
    for (int s = 0; s < 4; ++s) {
      const float* wp = W + (s * 32 + q * 8) * 64 + t * 16 + r16;
#pragma unroll
      for (int j = 0; j < 8; ++j) bf[t][s][j] = (h16)wp[j * 64];
    }
  long long base_row = (long long)blockIdx.x * 128 + wave * 32;
#pragma unroll
  for (int rt = 0; rt < 2; ++rt) {
    long long row0 = base_row + rt * 16;
    long long arow = row0 + r16;
    if (arow >= N) arow = N - 1;  // clamp loads; stores guarded below
    const float* xp = x + arow * 128 + q * 8;
    half8 af[4];
#pragma unroll
    for (int s = 0; s < 4; ++s) {
      float4 v0 = *(const float4*)(xp + s * 32);
      float4 v1 = *(const float4*)(xp + s * 32 + 4);
      af[s][0] = (h16)v0.x; af[s][1] = (h16)v0.y;
      af[s][2] = (h16)v0.z; af[s][3] = (h16)v0.w;
      af[s][4] = (h16)v1.x; af[s][5] = (h16)v1.y;
      af[s][6] = (h16)v1.z; af[s][7] = (h16)v1.w;
    }
    f32x4 acc[4] = {{0.f, 0.f, 0.f, 0.f}, {0.f, 0.f, 0.f, 0.f},
                    {0.f, 0.f, 0.f, 0.f}, {0.f, 0.f, 0.f, 0.f}};
#pragma unroll
    for (int s = 0; s < 4; ++s)
#pragma unroll
      for (int t = 0; t < 4; ++t)
        acc[t] = __builtin_amdgcn_mfma_f32_16x16x32_f16(af[s], bf[t][s], acc[t], 0, 0, 0);
#pragma unroll
    for (int t = 0; t < 4; ++t)
#pragma unroll
      for (int rr = 0; rr < 4; ++rr) {
        long long row = row0 + q * 4 + rr;
        if (row < N) h[row * 64 + t * 16 + r16] = (h16)acc[t][rr];
      }
  }
}

// ---------------------------------------------------------------- GEMM2 (MFMA): h[N,64](f16) = in[N,64](f16) @ W[64,64](f32)
__global__ __launch_bounds__(256, 1) void k_gemm2(const h16* __restrict__ xh,
                                                  const float* __restrict__ W,
                                                  h16* __restrict__ h, int N) {
  int lane = threadIdx.x & 63;
  int wave = threadIdx.x >> 6;
  int q = lane >> 4, r16 = lane & 15;
  half8 bf[4][2];
#pragma unroll
  for (int t = 0; t < 4; ++t)
#pragma unroll
    for (int s = 0; s < 2; ++s) {
      const float* wp = W + (s * 32 + q * 8) * 64 + t * 16 + r16;
#pragma unroll
      for (int j = 0; j < 8; ++j) bf[t][s][j] = (h16)wp[j * 64];
    }
  long long base_row = (long long)blockIdx.x * 128 + wave * 32;
#pragma unroll
  for (int rt = 0; rt < 2; ++rt) {
    long long row0 = base_row + rt * 16;
    long long arow = row0 + r16;
    if (arow >= N) arow = N - 1;
    half8 af[2];
#pragma unroll
    for (int s = 0; s < 2; ++s)
      af[s] = *(const half8*)(xh + arow * 64 + s * 32 + q * 8);
    f32x4 acc[4] = {{0.f, 0.f, 0.f, 0.f}, {0.f, 0.f, 0.f, 0.f},
                    {0.f, 0.f, 0.f, 0.f}, {0.f, 0.f, 0.f, 0.f}};
#pragma unroll
    for (int s = 0; s < 2; ++s)
#pragma unroll
      for (int t = 0; t < 4; ++t)
        acc[t] = __builtin_amdgcn_mfma_f32_16x16x32_f16(af[s], bf[t][s], acc[t], 0, 0, 0);
#pragma unroll
    for (int t = 0; t < 4; ++t)
#pragma unroll
      for (int rr = 0; rr < 4; ++rr) {
        long long row = row0 + q * 4 + rr;
        if (row < N) h[row * 64 + t * 16 + r16] = (h16)acc[t][rr];
      }
  }
}

// ---------------------------------------------------------------- CSR gather + self-loop + bias + BN + ReLU (fused, fp16 h)
__global__ __launch_bounds__(256) void k_gath(const int* __restrict__ csr,
                                              const int* __restrict__ offs,
                                              const float* __restrict__ dinv,
                                              const h16* __restrict__ hin,
                                              const float* __restrict__ b,
                                              const float* __restrict__ g,
                                              const float* __restrict__ be,
                                              const float* __restrict__ m,
                                              const float* __restrict__ v,
                                              h16* __restrict__ hout, int N) {
  int lane = threadIdx.x & 63;
  int node = (int)(((long long)blockIdx.x * blockDim.x + threadIdx.x) >> 6);
  if (node >= N) return;
  node = __builtin_amdgcn_readfirstlane(node);
  int beg = offs[node], end = offs[node + 1];
  float acc = 0.f;
  int j = beg;
  for (; j + 4 <= end; j += 4) {  // 4 independent row loads in flight
    int s0 = csr[j], s1 = csr[j + 1], s2 = csr[j + 2], s3 = csr[j + 3];
    float w0 = dinv[s0], w1 = dinv[s1], w2 = dinv[s2], w3 = dinv[s3];
    float h0 = (float)hin[(long long)s0 * 64 + lane];
    float h1 = (float)hin[(long long)s1 * 64 + lane];
    float h2 = (float)hin[(long long)s2 * 64 + lane];
    float h3 = (float)hin[(long long)s3 * 64 + lane];
    acc = fmaf(w0, h0, acc);
    acc = fmaf(w1, h1, acc);
    acc = fmaf(w2, h2, acc);
    acc = fmaf(w3, h3, acc);
  }
  for (; j < end; ++j) {
    int s = csr[j];
    acc = fmaf(dinv[s], (float)hin[(long long)s * 64 + lane], acc);
  }
  float di = dinv[node];
  acc = fmaf(di, (float)hin[(long long)node * 64 + lane], acc);  // self-loop
  acc = fmaf(di, acc, b[lane]);                                  // scale + bias
  float A = g[lane] * rsqrtf(v[lane] + EPSV);
  float B = be[lane] - m[lane] * A;
  hout[(long long)node * 64 + lane] = (h16)fmaxf(fmaf(acc, A, B), 0.f);
}

// ---------------------------------------------------------------- MLP head + sigmoid (fp16 input, already BN+ReLU)
__global__ __launch_bounds__(256) void k_cls(const h16* __restrict__ h,
                                             const float* __restrict__ Wc1,
                                             const float* __restrict__ bc1,
                                             const float* __restrict__ Wc2,
                                             const float* __restrict__ bc2,
                                             float* __restrict__ out, int N) {
  __shared__ float sW1[64 * 32];
  __shared__ float sW2[32];
  __shared__ float sb1[32];
  for (int i = threadIdx.x; i < 64 * 32; i += blockDim.x) sW1[i] = Wc1[i];
  if (threadIdx.x < 32) {
    sW2[threadIdx.x] = Wc2[threadIdx.x];
    sb1[threadIdx.x] = bc1[threadIdx.x];
  }
  __syncthreads();
  int node = blockIdx.x * blockDim.x + threadIdx.x;
  if (node >= N) return;
  const uint4* hp = (const uint4*)(h + (long long)node * 64);
  float mid[32];
#pragma unroll
  for (int j = 0; j < 32; ++j) mid[j] = sb1[j];
#pragma unroll
  for (int j4 = 0; j4 < 8; ++j4) {
    uint4 qv = hp[j4];
    unsigned int pk[4] = {qv.x, qv.y, qv.z, qv.w};
#pragma unroll
    for (int c = 0; c < 4; ++c) {
      float f0 = h2f(pk[c] & 0xffffu);
      float f1 = h2f(pk[c] >> 16);
      int f = j4 * 8 + c * 2;
#pragma unroll
      for (int j = 0; j < 32; ++j) mid[j] = fmaf(f0, sW1[f * 32 + j], mid[j]);
#pragma unroll
      for (int j = 0; j < 32; ++j) mid[j] = fmaf(f1, sW1[(f + 1) * 32 + j], mid[j]);
    }
  }
  float o = bc2[0];
#pragma unroll
  for (int j = 0; j < 32; ++j) o = fmaf(fmaxf(mid[j], 0.f), sW2[j], o);
  out[node] = 1.f / (1.f + expf(-o));
}

// ---------------------------------------------------------------- launch
extern "C" void kernel_launch(void* const* d_in, const int* in_sizes, int n_in,
                              void* d_out, int out_size, void* d_ws, size_t ws_size,
                              hipStream_t stream) {
  const float* x  = (const float*)d_in[0];
  const int* ei   = (const int*)d_in[1];
  const float* W1 = (const float*)d_in[2];
  const float* b1 = (const float*)d_in[3];
  const float* g1 = (const float*)d_in[4];
  const float* be1 = (const float*)d_in[5];
  const float* m1 = (const float*)d_in[6];
  const float* v1 = (const float*)d_in[7];
  const float* W2 = (const float*)d_in[8];
  const float* b2 = (const float*)d_in[9];
  const float* g2 = (const float*)d_in[10];
  const float* be2 = (const float*)d_in[11];
  const float* m2 = (const float*)d_in[12];
  const float* v2 = (const float*)d_in[13];
  const float* Wc1 = (const float*)d_in[14];
  const float* bc1 = (const float*)d_in[15];
  const float* Wc2 = (const float*)d_in[16];
  const float* bc2 = (const float*)d_in[17];
  float* out = (float*)d_out;

  int N = in_sizes[0] / 128;
  int E = in_sizes[1] / 2;
  int Npad = ((N + 63) / 64) * 64;
  int nb = (N + 1023) / 1024;
  int windows = (N + BINS - 1) / BINS;

  char* ws = (char*)d_ws;
  h16*   bufA  = (h16*)ws;                              // [N*64] fp16
  h16*   bufB  = bufA + (long long)N * 64;              // [N*64] fp16
  int*   csr   = (int*)(bufB + (long long)N * 64);      // [E]
  float* dinv  = (float*)(csr + E);                     // [Npad]
  int*   cnt   = (int*)(dinv + Npad);                   // [Npad]
  int*   offs  = cnt + Npad;                            // [Npad + 64]
  int*   cursor = offs + Npad + 64;                     // [Npad]
  int*   bsum  = cursor + Npad;                         // [512]
  size_t need = (size_t)((char*)(bsum + 512) - (char*)d_ws);
  if (need > ws_size) return;  // fail loudly rather than corrupt

  // ---- graph preprocessing (CSR build) ----
  k_zero<<<256, 256, 0, stream>>>((int4*)cnt, Npad / 4);
  k_deg2<<<windows * SLICES, 256, 0, stream>>>(ei, cnt, E, N);
  k_bsum<<<nb, 256, 0, stream>>>(cnt, bsum, N);
  k_bscan<<<1, 256, 0, stream>>>(bsum, nb, offs + N, E);
  k_scan3<<<nb, 256, 0, stream>>>(cnt, bsum, offs, cursor, dinv, N);
  k_scat2<<<windows * SLICES, 256, 0, stream>>>(ei, cursor, csr, E, N);

  // ---- layer 1 ----
  k_gemm1<<<(N + 127) / 128, 256, 0, stream>>>(x, W1, bufA, N);
  k_gath<<<(N * 64 + 255) / 256, 256, 0, stream>>>(csr, offs, dinv, bufA,
                                                   b1, g1, be1, m1, v1, bufB, N);
  // ---- layer 2 ----
  k_gemm2<<<(N + 127) / 128, 256, 0, stream>>>(bufB, W2, bufA, N);
  k_gath<<<(N * 64 + 255) / 256, 256, 0, stream>>>(csr, offs, dinv, bufA,
                                                   b2, g2, be2, m2, v2, bufB, N);
  // ---- classifier head ----
  k_cls<<<(N + 255) / 256, 256, 0, stream>>>(bufB, Wc1, bc1, Wc2, bc2, out, N);
}

// Round 7
// 362.019 us; speedup vs baseline: 1.3999x; 1.3999x over previous
//
#include <hip/hip_runtime.h>
#include <math.h>

#define EPSV 1e-5f
#define BINS 16384   // 64KB LDS histogram window
#define SLICES 64    // edge slices per window
#define HBLK 1024    // threads per histogram block (16 waves)

typedef _Float16 h16;
typedef _Float16 half8 __attribute__((ext_vector_type(8)));
typedef float f32x4 __attribute__((ext_vector_type(4)));

static __device__ __forceinline__ float h2f(unsigned int u16) {
  unsigned short s = (unsigned short)u16;
  h16 h;
  __builtin_memcpy(&h, &s, 2);
  return (float)h;
}

// ---------------------------------------------------------------- zero (int4)
__global__ __launch_bounds__(256) void k_zero(int4* p, long long n4) {
  long long i = (long long)blockIdx.x * blockDim.x + threadIdx.x;
  long long stride = (long long)gridDim.x * blockDim.x;
  for (; i < n4; i += stride) p[i] = make_int4(0, 0, 0, 0);
}

// ---------------------------------------------------------------- degree: LDS window histogram + coalesced merge
// grid = windows*SLICES; block (w,s): histogram slice s's dsts in window w.
__global__ __launch_bounds__(HBLK) void k_deg2(const int* __restrict__ ei,
                                               int* __restrict__ cnt, int E, int N) {
  __shared__ int hist[BINS];
  int w = blockIdx.x / SLICES, s = blockIdx.x % SLICES;
  int wlo = w * BINS, whi = wlo + BINS;
  long long elo = (long long)s * E / SLICES;
  long long ehi = (long long)(s + 1) * E / SLICES;
  for (int b = threadIdx.x; b < BINS; b += HBLK) hist[b] = 0;
  __syncthreads();
  for (long long i = elo + threadIdx.x; i < ehi; i += HBLK) {
    int d = ei[E + i];
    if (d >= wlo && d < whi) atomicAdd(&hist[d - wlo], 1);
  }
  __syncthreads();
  for (int b = threadIdx.x; b < BINS; b += HBLK) {
    int g = wlo + b;
    if (g < N && hist[b]) atomicAdd(&cnt[g], hist[b]);  // coalesced lanes
  }
}

// ---------------------------------------------------------------- scan step 1: per-1024-chunk sums
__global__ __launch_bounds__(256) void k_bsum(const int* __restrict__ cnt,
                                              int* __restrict__ bsum, int N) {
  int b = blockIdx.x, t = threadIdx.x;
  int base = b << 10;
  int v = 0;
#pragma unroll
  for (int i = 0; i < 4; ++i) {
    int idx = base + t + i * 256;
    if (idx < N) v += cnt[idx];
  }
  __shared__ int s[256];
  s[t] = v;
  __syncthreads();
  for (int off = 128; off > 0; off >>= 1) {
    if (t < off) s[t] += s[t + off];
    __syncthreads();
  }
  if (t == 0) bsum[b] = s[0];
}

// ---------------------------------------------------------------- scan step 2: exclusive scan of chunk sums (1 block)
__global__ __launch_bounds__(256) void k_bscan(int* __restrict__ bsum, int nb,
                                               int* __restrict__ offs_last, int E) {
  int t = threadIdx.x;
  int per = (nb + 255) / 256;
  int lo = t * per, hi = min(lo + per, nb);
  int tot = 0;
  for (int i = lo; i < hi; ++i) tot += bsum[i];
  __shared__ int s[256];
  s[t] = tot;
  __syncthreads();
  for (int off = 1; off < 256; off <<= 1) {
    int u = (t >= off) ? s[t - off] : 0;
    __syncthreads();
    s[t] += u;
    __syncthreads();
  }
  int run = s[t] - tot;
  for (int i = lo; i < hi; ++i) {
    int v = bsum[i];
    bsum[i] = run;
    run += v;
  }
  if (t == 0) *offs_last = E;  // offs[N] = E
}

// ---------------------------------------------------------------- scan step 3: per-chunk exclusive scan + base; offs, cursor, dinv
__global__ __launch_bounds__(256) void k_scan3(const int* __restrict__ cnt,
                                               const int* __restrict__ bsum,
                                               int* __restrict__ offs,
                                               int* __restrict__ cursor,
                                               float* __restrict__ dinv, int N) {
  int b = blockIdx.x, t = threadIdx.x;
  int base = (b << 10) + t * 4;
  int c[4];
  int tot = 0;
#pragma unroll
  for (int i = 0; i < 4; ++i) {
    int idx = base + i;
    c[i] = (idx < N) ? cnt[idx] : 0;
    tot += c[i];
  }
  __shared__ int s[256];
  s[t] = tot;
  __syncthreads();
  for (int off = 1; off < 256; off <<= 1) {
    int u = (t >= off) ? s[t - off] : 0;
    __syncthreads();
    s[t] += u;
    __syncthreads();
  }
  int run = s[t] - tot + bsum[b];
#pragma unroll
  for (int i = 0; i < 4; ++i) {
    int idx = base + i;
    if (idx < N) {
      offs[idx] = run;
      cursor[idx] = run;
      dinv[idx] = rsqrtf((float)c[i] + 1.f);
      run += c[i];
    }
  }
}

// ---------------------------------------------------------------- CSR scatter: LDS hist + bulk reserve + LDS cursor alloc
__global__ __launch_bounds__(HBLK) void k_scat2(const int* __restrict__ ei,
                                                int* __restrict__ cursor,
                                                int* __restrict__ csr, int E, int N) {
  __shared__ int hist[BINS];
  int w = blockIdx.x / SLICES, s = blockIdx.x % SLICES;
  int wlo = w * BINS, whi = wlo + BINS;
  long long elo = (long long)s * E / SLICES;
  long long ehi = (long long)(s + 1) * E / SLICES;
  for (int b = threadIdx.x; b < BINS; b += HBLK) hist[b] = 0;
  __syncthreads();
  for (long long i = elo + threadIdx.x; i < ehi; i += HBLK) {
    int d = ei[E + i];
    if (d >= wlo && d < whi) atomicAdd(&hist[d - wlo], 1);
  }
  __syncthreads();
  for (int b = threadIdx.x; b < BINS; b += HBLK) {
    int g = wlo + b;
    int h = hist[b];
    int base = 0;
    if (g < N && h) base = atomicAdd(&cursor[g], h);  // coalesced reserve
    hist[b] = base;                                   // LDS bin cursor
  }
  __syncthreads();
  for (long long i = elo + threadIdx.x; i < ehi; i += HBLK) {
    int d = ei[E + i];                                // L2-hot (pass-1 read)
    if (d >= wlo && d < whi) {
      int pos = atomicAdd(&hist[d - wlo], 1);         // ds_add_rtn
      csr[pos] = ei[i];                               // window-dense write
    }
  }
}

// ---------------------------------------------------------------- GEMM1 (MFMA): h[N,64](f16) = x[N,128](f32) @ W[128,64](f32)
// A: row=lane&15, k=(lane>>4)*8+j ; B: col=lane&15, same k ;
// D: col=lane&15, row=(lane>>4)*4+reg   [m89/m91-verified layouts]
__global__ __launch_bounds__(256, 1) void k_gemm1(const float* __restrict__ x,
                                                  const float* __restrict__ W,
                                                  h16* __restrict__ h, int N) {
  int lane = threadIdx.x & 63;
  int wave = threadIdx.x >> 6;
  int q = lane >> 4, r16 = lane & 15;
  half8 bf[4][4];  // [n_tile][k_step], W is L2-resident
#pragma unroll
  for (int t = 0; t < 4; ++t)
#pragma unroll
    for (int s = 0; s < 4; ++s) {
      const float* wp = W + (s * 32 + q * 8) * 64 + t * 16 + r16;
#pragma unroll
      for (int j = 0; j < 8; ++j) bf[t][s][j] = (h16)wp[j * 64];
    }
  long long base_row = (long long)blockIdx.x * 128 + wave * 32;
#pragma unroll
  for (int rt = 0; rt < 2; ++rt) {
    long long row0 = base_row + rt * 16;
    long long arow = row0 + r16;
    if (arow >= N) arow = N - 1;  // clamp loads; stores guarded below
    const float* xp = x + arow * 128 + q * 8;
    half8 af[4];
#pragma unroll
    for (int s = 0; s < 4; ++s) {
      float4 v0 = *(const float4*)(xp + s * 32);
      float4 v1 = *(const float4*)(xp + s * 32 + 4);
      af[s][0] = (h16)v0.x; af[s][1] = (h16)v0.y;
      af[s][2] = (h16)v0.z; af[s][3] = (h16)v0.w;
      af[s][4] = (h16)v1.x; af[s][5] = (h16)v1.y;
      af[s][6] = (h16)v1.z; af[s][7] = (h16)v1.w;
    }
    f32x4 acc[4] = {{0.f, 0.f, 0.f, 0.f}, {0.f, 0.f, 0.f, 0.f},
                    {0.f, 0.f, 0.f, 0.f}, {0.f, 0.f, 0.f, 0.f}};
#pragma unroll
    for (int s = 0; s < 4; ++s)
#pragma unroll
      for (int t = 0; t < 4; ++t)
        acc[t] = __builtin_amdgcn_mfma_f32_16x16x32_f16(af[s], bf[t][s], acc[t], 0, 0, 0);
#pragma unroll
    for (int t = 0; t < 4; ++t)
#pragma unroll
      for (int rr = 0; rr < 4; ++rr) {
        long long row = row0 + q * 4 + rr;
        if (row < N) h[row * 64 + t * 16 + r16] = (h16)acc[t][rr];
      }
  }
}

// ---------------------------------------------------------------- GEMM2 (MFMA): h[N,64](f16) = in[N,64](f16) @ W[64,64](f32)
__global__ __launch_bounds__(256, 1) void k_gemm2(const h16* __restrict__ xh,
                                                  const float* __restrict__ W,
                                                  h16* __restrict__ h, int N) {
  int lane = threadIdx.x & 63;
  int wave = threadIdx.x >> 6;
  int q = lane >> 4, r16 = lane & 15;
  half8 bf[4][2];
#pragma unroll
  for (int t = 0; t < 4; ++t)
#pragma unroll
    for (int s = 0; s < 2; ++s) {
      const float* wp = W + (s * 32 + q * 8) * 64 + t * 16 + r16;
#pragma unroll
      for (int j = 0; j < 8; ++j) bf[t][s][j] = (h16)wp[j * 64];
    }
  long long base_row = (long long)blockIdx.x * 128 + wave * 32;
#pragma unroll
  for (int rt = 0; rt < 2; ++rt) {
    long long row0 = base_row + rt * 16;
    long long arow = row0 + r16;
    if (arow >= N) arow = N - 1;
    half8 af[2];
#pragma unroll
    for (int s = 0; s < 2; ++s)
      af[s] = *(const half8*)(xh + arow * 64 + s * 32 + q * 8);
    f32x4 acc[4] = {{0.f, 0.f, 0.f, 0.f}, {0.f, 0.f, 0.f, 0.f},
                    {0.f, 0.f, 0.f, 0.f}, {0.f, 0.f, 0.f, 0.f}};
#pragma unroll
    for (int s = 0; s < 2; ++s)
#pragma unroll
      for (int t = 0; t < 4; ++t)
        acc[t] = __builtin_amdgcn_mfma_f32_16x16x32_f16(af[s], bf[t][s], acc[t], 0, 0, 0);
#pragma unroll
    for (int t = 0; t < 4; ++t)
#pragma unroll
      for (int rr = 0; rr < 4; ++rr) {
        long long row = row0 + q * 4 + rr;
        if (row < N) h[row * 64 + t * 16 + r16] = (h16)acc[t][rr];
      }
  }
}

// ---------------------------------------------------------------- CSR gather + self-loop + bias + BN + ReLU (fused, fp16 h)
__global__ __launch_bounds__(256) void k_gath(const int* __restrict__ csr,
                                              const int* __restrict__ offs,
                                              const float* __restrict__ dinv,
                                              const h16* __restrict__ hin,
                                              const float* __restrict__ b,
                                              const float* __restrict__ g,
                                              const float* __restrict__ be,
                                              const float* __restrict__ m,
                                              const float* __restrict__ v,
                                              h16* __restrict__ hout, int N) {
  int lane = threadIdx.x & 63;
  int node = (int)(((long long)blockIdx.x * blockDim.x + threadIdx.x) >> 6);
  if (node >= N) return;
  node = __builtin_amdgcn_readfirstlane(node);
  int beg = offs[node], end = offs[node + 1];
  float acc = 0.f;
  int j = beg;
  for (; j + 4 <= end; j += 4) {  // 4 independent row loads in flight
    int s0 = csr[j], s1 = csr[j + 1], s2 = csr[j + 2], s3 = csr[j + 3];
    float w0 = dinv[s0], w1 = dinv[s1], w2 = dinv[s2], w3 = dinv[s3];
    float h0 = (float)hin[(long long)s0 * 64 + lane];
    float h1 = (float)hin[(long long)s1 * 64 + lane];
    float h2 = (float)hin[(long long)s2 * 64 + lane];
    float h3 = (float)hin[(long long)s3 * 64 + lane];
    acc = fmaf(w0, h0, acc);
    acc = fmaf(w1, h1, acc);
    acc = fmaf(w2, h2, acc);
    acc = fmaf(w3, h3, acc);
  }
  for (; j < end; ++j) {
    int s = csr[j];
    acc = fmaf(dinv[s], (float)hin[(long long)s * 64 + lane], acc);
  }
  float di = dinv[node];
  acc = fmaf(di, (float)hin[(long long)node * 64 + lane], acc);  // self-loop
  acc = fmaf(di, acc, b[lane]);                                  // scale + bias
  float A = g[lane] * rsqrtf(v[lane] + EPSV);
  float B = be[lane] - m[lane] * A;
  hout[(long long)node * 64 + lane] = (h16)fmaxf(fmaf(acc, A, B), 0.f);
}

// ---------------------------------------------------------------- MLP head + sigmoid (fp16 input, already BN+ReLU)
__global__ __launch_bounds__(256) void k_cls(const h16* __restrict__ h,
                                             const float* __restrict__ Wc1,
                                             const float* __restrict__ bc1,
                                             const float* __restrict__ Wc2,
                                             const float* __restrict__ bc2,
                                             float* __restrict__ out, int N) {
  __shared__ float sW1[64 * 32];
  __shared__ float sW2[32];
  __shared__ float sb1[32];
  for (int i = threadIdx.x; i < 64 * 32; i += blockDim.x) sW1[i] = Wc1[i];
  if (threadIdx.x < 32) {
    sW2[threadIdx.x] = Wc2[threadIdx.x];
    sb1[threadIdx.x] = bc1[threadIdx.x];
  }
  __syncthreads();
  int node = blockIdx.x * blockDim.x + threadIdx.x;
  if (node >= N) return;
  const uint4* hp = (const uint4*)(h + (long long)node * 64);
  float mid[32];
#pragma unroll
  for (int j = 0; j < 32; ++j) mid[j] = sb1[j];
#pragma unroll
  for (int j4 = 0; j4 < 8; ++j4) {
    uint4 qv = hp[j4];
    unsigned int pk[4] = {qv.x, qv.y, qv.z, qv.w};
#pragma unroll
    for (int c = 0; c < 4; ++c) {
      float f0 = h2f(pk[c] & 0xffffu);
      float f1 = h2f(pk[c] >> 16);
      int f = j4 * 8 + c * 2;
#pragma unroll
      for (int j = 0; j < 32; ++j) mid[j] = fmaf(f0, sW1[f * 32 + j], mid[j]);
#pragma unroll
      for (int j = 0; j < 32; ++j) mid[j] = fmaf(f1, sW1[(f + 1) * 32 + j], mid[j]);
    }
  }
  float o = bc2[0];
#pragma unroll
  for (int j = 0; j < 32; ++j) o = fmaf(fmaxf(mid[j], 0.f), sW2[j], o);
  out[node] = 1.f / (1.f + expf(-o));
}

// ---------------------------------------------------------------- launch
extern "C" void kernel_launch(void* const* d_in, const int* in_sizes, int n_in,
                              void* d_out, int out_size, void* d_ws, size_t ws_size,
                              hipStream_t stream) {
  const float* x  = (const float*)d_in[0];
  const int* ei   = (const int*)d_in[1];
  const float* W1 = (const float*)d_in[2];
  const float* b1 = (const float*)d_in[3];
  const float* g1 = (const float*)d_in[4];
  const float* be1 = (const float*)d_in[5];
  const float* m1 = (const float*)d_in[6];
  const float* v1 = (const float*)d_in[7];
  const float* W2 = (const float*)d_in[8];
  const float* b2 = (const float*)d_in[9];
  const float* g2 = (const float*)d_in[10];
  const float* be2 = (const float*)d_in[11];
  const float* m2 = (const float*)d_in[12];
  const float* v2 = (const float*)d_in[13];
  const float* Wc1 = (const float*)d_in[14];
  const float* bc1 = (const float*)d_in[15];
  const float* Wc2 = (const float*)d_in[16];
  const float* bc2 = (const float*)d_in[17];
  float* out = (float*)d_out;

  int N = in_sizes[0] / 128;
  int E = in_sizes[1] / 2;
  int Npad = ((N + 63) / 64) * 64;
  int nb = (N + 1023) / 1024;
  int windows = (N + BINS - 1) / BINS;

  char* ws = (char*)d_ws;
  h16*   bufA  = (h16*)ws;                              // [N*64] fp16
  h16*   bufB  = bufA + (long long)N * 64;              // [N*64] fp16
  int*   csr   = (int*)(bufB + (long long)N * 64);      // [E]
  float* dinv  = (float*)(csr + E);                     // [Npad]
  int*   cnt   = (int*)(dinv + Npad);                   // [Npad]
  int*   offs  = cnt + Npad;                            // [Npad + 64]
  int*   cursor = offs + Npad + 64;                     // [Npad]
  int*   bsum  = cursor + Npad;                         // [512]
  size_t need = (size_t)((char*)(bsum + 512) - (char*)d_ws);
  if (need > ws_size) return;  // fail loudly rather than corrupt

  // ---- graph preprocessing (CSR build) ----
  k_zero<<<256, 256, 0, stream>>>((int4*)cnt, Npad / 4);
  k_deg2<<<windows * SLICES, HBLK, 0, stream>>>(ei, cnt, E, N);
  k_bsum<<<nb, 256, 0, stream>>>(cnt, bsum, N);
  k_bscan<<<1, 256, 0, stream>>>(bsum, nb, offs + N, E);
  k_scan3<<<nb, 256, 0, stream>>>(cnt, bsum, offs, cursor, dinv, N);
  k_scat2<<<windows * SLICES, HBLK, 0, stream>>>(ei, cursor, csr, E, N);

  // ---- layer 1 ----
  k_gemm1<<<(N + 127) / 128, 256, 0, stream>>>(x, W1, bufA, N);
  k_gath<<<(N * 64 + 255) / 256, 256, 0, stream>>>(csr, offs, dinv, bufA,
                                                   b1, g1, be1, m1, v1, bufB, N);
  // ---- layer 2 ----
  k_gemm2<<<(N + 127) / 128, 256, 0, stream>>>(bufB, W2, bufA, N);
  k_gath<<<(N * 64 + 255) / 256, 256, 0, stream>>>(csr, offs, dinv, bufA,
                                                   b2, g2, be2, m2, v2, bufB, N);
  // ---- classifier head ----
  k_cls<<<(N + 255) / 256, 256, 0, stream>>>(bufB, Wc1, bc1, Wc2, bc2, out, N);
}